// Round 11
// baseline (581.665 us; speedup 1.0000x reference)
//
#include <hip/hip_runtime.h>

#define M_TOT 32768  // B*N

typedef float f32x4 __attribute__((ext_vector_type(4)));
typedef short s16x8 __attribute__((ext_vector_type(8)));

#define AS1(p) ((__attribute__((address_space(1))) void*)(p))
#define AS3(p) ((__attribute__((address_space(3))) void*)(p))

#define BARRIER() asm volatile("s_barrier" ::: "memory")
#define VMCNT4() asm volatile("s_waitcnt vmcnt(4)" ::: "memory")
#define VMCNT2() asm volatile("s_waitcnt vmcnt(2)" ::: "memory")
#define VMCNT0() asm volatile("s_waitcnt vmcnt(0)" ::: "memory")

__device__ __forceinline__ short f2bf(float f) {
    unsigned u = __builtin_bit_cast(unsigned, f);
    u += 0x7fffu + ((u >> 16) & 1u);
    return (short)(u >> 16);
}
__device__ __forceinline__ float bf2f(short s) {
    unsigned u = ((unsigned)(unsigned short)s) << 16;
    return __builtin_bit_cast(float, u);
}

// ---- merged prep: conv_x (blocks 0..2047) + conv_w transpose (2048..3327) + bias (3328..3347) ----
__global__ __launch_bounds__(256) void prep(const float* __restrict__ x, short* __restrict__ y,
                                            const float* __restrict__ Wq, const float* __restrict__ Wk,
                                            const float* __restrict__ Wv, const float* __restrict__ Wu,
                                            const float* __restrict__ Wo, short* __restrict__ Wcat,
                                            const float* __restrict__ bq, const float* __restrict__ bk,
                                            const float* __restrict__ bv, const float* __restrict__ bu,
                                            const float* __restrict__ bo, float* __restrict__ bcat) {
    __shared__ float t[64][65];
    const int blk = blockIdx.x;
    if (blk < 2048) {
        const size_t nchunk = (size_t)M_TOT * 1024 / 8;
        const size_t stride = (size_t)2048 * 256;
        for (size_t c = (size_t)blk * 256 + threadIdx.x; c < nchunk; c += stride) {
            const float4* src = (const float4*)(x + c * 8);
            float4 a = src[0], b = src[1];
            s16x8 r;
            r[0] = f2bf(a.x); r[1] = f2bf(a.y); r[2] = f2bf(a.z); r[3] = f2bf(a.w);
            r[4] = f2bf(b.x); r[5] = f2bf(b.y); r[6] = f2bf(b.z); r[7] = f2bf(b.w);
            *(s16x8*)(y + c * 8) = r;
        }
    } else if (blk < 3328) {
        const int b = blk - 2048;           // 0..1279
        const int mat = b >> 8;             // 0..4
        const int kt = (b >> 4) & 15, nt = b & 15;
        const int k0 = kt << 6, n0 = nt << 6;
        const float* W = (mat == 0) ? Wq : (mat == 1) ? Wk : (mat == 2) ? Wv
                       : (mat == 3) ? Wu : Wo;
        const int rr = threadIdx.x >> 4;    // 0..15
        const int cc = threadIdx.x & 15;    // 0..15
        #pragma unroll
        for (int p = 0; p < 4; ++p) {
            const int row = p * 16 + rr;
            const float4 v = *(const float4*)(W + (size_t)(k0 + row) * 1024 + n0 + cc * 4);
            t[row][cc * 4 + 0] = v.x; t[row][cc * 4 + 1] = v.y;
            t[row][cc * 4 + 2] = v.z; t[row][cc * 4 + 3] = v.w;
        }
        __syncthreads();
        #pragma unroll
        for (int p = 0; p < 4; ++p) {
            const int nr = p * 16 + rr;
            short4 r;
            r.x = f2bf(t[cc * 4 + 0][nr]); r.y = f2bf(t[cc * 4 + 1][nr]);
            r.z = f2bf(t[cc * 4 + 2][nr]); r.w = f2bf(t[cc * 4 + 3][nr]);
            *(short4*)(Wcat + (size_t)(mat * 1024 + n0 + nr) * 1024 + k0 + cc * 4) = r;
        }
    } else {
        const int i = (blk - 3328) * 256 + threadIdx.x;  // < 5120
        const float* b = (i < 1024) ? bq : (i < 2048) ? bk : (i < 3072) ? bv
                       : (i < 4096) ? bu : bo;
        bcat[i] = b[i & 1023];
    }
}

// ---- 256x256 GEMM, BK=64, 2 LDS buffers, 2 free-running windows/K-tile (r5 best, FROZEN) ----
template <int MODE>
__global__ __launch_bounds__(512, 2) void gemm8(
        const short* __restrict__ A, const short* __restrict__ W,
        const float* __restrict__ bias,
        short* __restrict__ qb, short* __restrict__ ktb,
        short* __restrict__ vtb, short* __restrict__ ub,
        float* __restrict__ outb) {
    extern __shared__ char lds[];
    const int tid = threadIdx.x;
    const int wave = tid >> 6, lane = tid & 63;
    const int r16 = lane & 15, g = lane >> 4;
    const int moff = (wave >> 2) << 7;  // 0 / 128
    const int noff = (wave & 3) << 6;   // 0 / 64 / 128 / 192

    const int nwg = (MODE == 0) ? 2048 : 512;
    const int NB = (MODE == 0) ? 16 : 4;
    const int bid = blockIdx.x;
    const int swz = (bid & 7) * (nwg >> 3) + (bid >> 3);  // XCD-chunked (nwg%8==0)
    const int mblk = swz / NB, nblk = swz % NB;           // M-outer: XCDs own disjoint A-slices
    const int row0 = mblk << 8, col0 = nblk << 8;

    // ds_read swizzled chunk offsets (lane-constant)
    const int rswz = r16 & 7;
    const int ck0 = (g ^ rswz) << 4;
    const int ck1 = ((4 + g) ^ rswz) << 4;
    const int rowbA = (moff + r16) << 7;
    const int rowbB = (noff + r16) << 7;

    // staging source (lane-constant): row-in-inst = wave*8 + (lane>>3), chunk pre-swizzled
    const char* baseA = (const char*)A + (size_t)(row0 + wave * 8 + (lane >> 3)) * 2048
                        + (((lane & 7) ^ ((lane >> 3) & 7)) << 4);
    const char* baseB = (const char*)W + (size_t)(col0 + wave * 8 + (lane >> 3)) * 2048
                        + (((lane & 7) ^ ((lane >> 3) & 7)) << 4);

#define STG(BASE, J, T, DST)                                                   \
    __builtin_amdgcn_global_load_lds(                                          \
        AS1((BASE) + (size_t)(J) * 131072 + (size_t)(T) * 128),                \
        AS3((DST) + (J) * 8192 + wave * 1024), 16, 0, 0)

#define RDA(V, M, BUFA) {                                                      \
    (V)[0] = *(const s16x8*)((BUFA) + rowbA + (M) * 2048 + ck0);               \
    (V)[1] = *(const s16x8*)((BUFA) + rowbA + (M) * 2048 + ck1); }

#define RDB(V, N, BUFB) {                                                      \
    (V)[0] = *(const s16x8*)((BUFB) + rowbB + (N) * 2048 + ck0);               \
    (V)[1] = *(const s16x8*)((BUFB) + rowbB + (N) * 2048 + ck1); }

#define MF16(P, A0, A1)                                                        \
    _Pragma("unroll") for (int kk = 0; kk < 2; ++kk)                           \
        _Pragma("unroll") for (int n = 0; n < 4; ++n) {                        \
            acc[2*(P)][n]   = __builtin_amdgcn_mfma_f32_16x16x32_bf16((A0)[kk], bfr[n][kk], acc[2*(P)][n], 0, 0, 0);   \
            acc[2*(P)+1][n] = __builtin_amdgcn_mfma_f32_16x16x32_bf16((A1)[kk], bfr[n][kk], acc[2*(P)+1][n], 0, 0, 0); \
        }

#define TILE(T, DOSTAGE, TRmid, TRend) {                                       \
    char* bA_ = lds + ((T) & 1) * 65536; char* bB_ = bA_ + 32768;              \
    char* sA_ = lds + (((T) + 1) & 1) * 65536; char* sB_ = sA_ + 32768;        \
    s16x8 a0[2], a1[2], a2[2], a3[2];                                          \
    if (DOSTAGE) { STG(baseB, 0, (T) + 1, sB_); STG(baseB, 1, (T) + 1, sB_);   \
                   STG(baseB, 2, (T) + 1, sB_); STG(baseB, 3, (T) + 1, sB_); } \
    _Pragma("unroll") for (int n = 0; n < 4; ++n) RDB(bfr[n], n, bB_);         \
    RDA(a0, 0, bA_); RDA(a1, 1, bA_); RDA(a2, 2, bA_); RDA(a3, 3, bA_);        \
    __builtin_amdgcn_s_setprio(1);                                             \
    MF16(0, a0, a1); MF16(1, a2, a3);                                          \
    __builtin_amdgcn_s_setprio(0);                                             \
    TRmid; BARRIER();                                                          \
    if (DOSTAGE) { STG(baseA, 0, (T) + 1, sA_); STG(baseA, 2, (T) + 1, sA_);   \
                   STG(baseA, 1, (T) + 1, sA_); STG(baseA, 3, (T) + 1, sA_); } \
    RDA(a0, 4, bA_); RDA(a1, 5, bA_); RDA(a2, 6, bA_); RDA(a3, 7, bA_);        \
    __builtin_amdgcn_s_setprio(1);                                             \
    MF16(2, a0, a1); MF16(3, a2, a3);                                          \
    __builtin_amdgcn_s_setprio(0);                                             \
    TRend; BARRIER(); }

    f32x4 acc[8][4] = {};
    s16x8 bfr[4][2];

    // prologue: stage tile 0 in steady-state issue order, keep A1,A3 in flight
    STG(baseB, 0, 0, lds + 32768); STG(baseB, 1, 0, lds + 32768);
    STG(baseB, 2, 0, lds + 32768); STG(baseB, 3, 0, lds + 32768);
    STG(baseA, 0, 0, lds);         STG(baseA, 2, 0, lds);
    STG(baseA, 1, 0, lds);         STG(baseA, 3, 0, lds);
    VMCNT2();
    BARRIER();

    #pragma unroll 1
    for (int t = 0; t < 15; ++t) TILE(t, true, VMCNT4(), VMCNT2());
    TILE(15, false, VMCNT0(), (void)0);

    // ---- epilogue ----
    const int rj = (lane >> 4) << 2;
    if (MODE == 1) {
        #pragma unroll
        for (int n = 0; n < 4; ++n) {
            const int gn = col0 + noff + n * 16 + r16;
            const float bv = bias[gn];
            #pragma unroll
            for (int m = 0; m < 8; ++m) {
                const int gm0 = row0 + moff + m * 16 + rj;
                #pragma unroll
                for (int j = 0; j < 4; ++j)
                    outb[(size_t)(gm0 + j) * 1024 + gn] = acc[m][n][j] + bv;
            }
        }
    } else {
        const int seg = col0 >> 10;  // block-uniform (256-col block within one 1024 seg)
        if (seg == 0 || seg == 3) {
            short* dst = (seg == 0) ? qb : ub;
            const bool do_relu = (seg == 0);
            #pragma unroll
            for (int n = 0; n < 4; ++n) {
                const int gn = col0 + noff + n * 16 + r16;
                const int f = gn & 1023;
                const float bv = bias[gn];
                #pragma unroll
                for (int m = 0; m < 8; ++m) {
                    const int gm0 = row0 + moff + m * 16 + rj;
                    #pragma unroll
                    for (int j = 0; j < 4; ++j) {
                        float val = acc[m][n][j] + bv;
                        if (do_relu) val = fmaxf(val, 0.0f);
                        dst[(size_t)(gm0 + j) * 1024 + f] = f2bf(val);
                    }
                }
            }
        } else {
            short* dst = (seg == 1) ? ktb : vtb;
            const bool do_relu = (seg == 1);
            #pragma unroll
            for (int n = 0; n < 4; ++n) {
                const int gn = col0 + noff + n * 16 + r16;
                const int hd = gn & 1023;  // h*64+d
                const float bv = bias[gn];
                #pragma unroll
                for (int m = 0; m < 8; ++m) {
                    const int gm0 = row0 + moff + m * 16 + rj;  // token, multiple of 4
                    const int b = gm0 >> 13;
                    const int ntok = gm0 & 8191;
                    float v0 = acc[m][n][0] + bv, v1 = acc[m][n][1] + bv;
                    float v2 = acc[m][n][2] + bv, v3 = acc[m][n][3] + bv;
                    if (do_relu) {
                        v0 = fmaxf(v0, 0.0f); v1 = fmaxf(v1, 0.0f);
                        v2 = fmaxf(v2, 0.0f); v3 = fmaxf(v3, 0.0f);
                    }
                    short4 pk;
                    pk.x = f2bf(v0); pk.y = f2bf(v1); pk.z = f2bf(v2); pk.w = f2bf(v3);
                    *(short4*)(dst + ((size_t)(b * 1024 + hd)) * 8192 + ntok) = pk;
                }
            }
        }
    }
#undef TILE
#undef MF16
#undef RDB
#undef RDA
#undef STG
}

// ---- kv partials: 4-wave block per (slice, bh); 1024 tokens; LDS cross-wave reduce ----
__global__ __launch_bounds__(256) void kv_partial(const short* __restrict__ ktb,
                                                  const short* __restrict__ vtb,
                                                  float* __restrict__ kvp) {
    __shared__ float red[4][4096];  // 64 KB
    const int slice = blockIdx.x;  // 0..7
    const int bh = blockIdx.y;     // 0..63
    const int wave = threadIdx.x >> 6, lane = threadIdx.x & 63;
    const int r16 = lane & 15;
    const short* kb = ktb + (size_t)bh * 64 * 8192;
    const short* vb = vtb + (size_t)bh * 64 * 8192;
    const int n0 = (slice << 10) + (wave << 8);
    f32x4 acc[4][4] = {};
    for (int s = 0; s < 8; ++s) {
        const int nk = n0 + (s << 5) + ((lane >> 4) << 3);
        s16x8 af[4], bf[4];
        #pragma unroll
        for (int m = 0; m < 4; ++m) af[m] = *(const s16x8*)(kb + (size_t)(m * 16 + r16) * 8192 + nk);
        #pragma unroll
        for (int n = 0; n < 4; ++n) bf[n] = *(const s16x8*)(vb + (size_t)(n * 16 + r16) * 8192 + nk);
        #pragma unroll
        for (int m = 0; m < 4; ++m)
            #pragma unroll
            for (int n = 0; n < 4; ++n)
                acc[m][n] = __builtin_amdgcn_mfma_f32_16x16x32_bf16(af[m], bf[n], acc[m][n], 0, 0, 0);
    }
    const int rj = (lane >> 4) << 2;
    #pragma unroll
    for (int m = 0; m < 4; ++m)
        #pragma unroll
        for (int n = 0; n < 4; ++n)
            #pragma unroll
            for (int j = 0; j < 4; ++j)
                red[wave][(m * 16 + rj + j) * 64 + n * 16 + r16] = acc[m][n][j];
    __syncthreads();
    float* dst = kvp + ((size_t)slice * 64 + bh) * 4096;
    const int i0 = threadIdx.x * 16;
    #pragma unroll
    for (int e = 0; e < 16; e += 4) {
        f32x4 a0 = *(const f32x4*)&red[0][i0 + e];
        f32x4 a1 = *(const f32x4*)&red[1][i0 + e];
        f32x4 a2 = *(const f32x4*)&red[2][i0 + e];
        f32x4 a3 = *(const f32x4*)&red[3][i0 + e];
        *(f32x4*)&dst[i0 + e] = (a0 + a1) + (a2 + a3);
    }
}

// ---- reduce 8 kv partials, abs-clamp, store transposed bf16 kv_t[bh][e][d]; 512 blocks ----
__global__ void kv_reduce(const float* __restrict__ kvp, short* __restrict__ kvt) {
    const int bh = blockIdx.x >> 3;
    const int seg = blockIdx.x & 7;
    const int i = (seg << 9) + threadIdx.x * 2;
    #pragma unroll
    for (int p = 0; p < 2; ++p) {
        const int ii = i + p;
        float s = 0.0f;
        #pragma unroll
        for (int sl = 0; sl < 8; ++sl)
            s += kvp[((size_t)sl * 64 + bh) * 4096 + ii];
        float a = fabsf(s);
        float cmag = fminf(fmaxf(a, 0.01f), 100.0f);
        float r = (s > 0.0f) ? cmag : ((s < 0.0f) ? -cmag : 0.0f);
        const int d = ii >> 6, e = ii & 63;
        kvt[(size_t)bh * 4096 + e * 64 + d] = f2bf(r);
    }
}

// ---- fused o = q @ kv -> LayerNorm -> * u -> y (bf16), SINGLE MFMA pass ----
// o kept in REGISTERS as packed bf16 (s16x8 keep[16][2], static indices only);
// pass 2 unpacks, applies LN, and reuses the proven 2KB swizzled wave transpose
// for coalesced u-mul/store. No q re-read, no MFMA recompute.
__global__ __launch_bounds__(256) void qkv_ln(const short* __restrict__ qb,
                                              const short* __restrict__ kvt,
                                              const short* __restrict__ ub,
                                              const float* __restrict__ lnw,
                                              const float* __restrict__ lnb,
                                              short* __restrict__ yb) {
    __shared__ short tr[4][1024];  // 2 KB per wave
    const int wave = threadIdx.x >> 6, lane = threadIdx.x & 63;
    const int r16 = lane & 15, g = lane >> 4;
    const size_t rowB = (size_t)blockIdx.x * 64 + wave * 16;
    const int bh0 = (int)((rowB >> 13) << 4);
    const short* qrow = qb + (rowB + r16) * 1024 + g * 8;

    s16x8 keep[16][2];
    float s[4] = {0, 0, 0, 0}, sq[4] = {0, 0, 0, 0};
    #pragma unroll
    for (int h = 0; h < 16; ++h) {
        const short* kvb = kvt + (size_t)(bh0 + h) * 4096 + g * 8;
        f32x4 a4[4] = {};
        #pragma unroll
        for (int kk = 0; kk < 2; ++kk) {
            const s16x8 af = *(const s16x8*)(qrow + h * 64 + kk * 32);
            #pragma unroll
            for (int n = 0; n < 4; ++n) {
                const s16x8 bf = *(const s16x8*)(kvb + (n * 16 + r16) * 64 + kk * 32);
                a4[n] = __builtin_amdgcn_mfma_f32_16x16x32_bf16(af, bf, a4[n], 0, 0, 0);
            }
        }
        #pragma unroll
        for (int n = 0; n < 4; ++n)
            #pragma unroll
            for (int j = 0; j < 4; ++j) {
                const float v = a4[n][j];
                s[j] += v; sq[j] += v * v;
                keep[h][n >> 1][(n & 1) * 4 + j] = f2bf(v);
            }
    }
    #pragma unroll
    for (int j = 0; j < 4; ++j) {
        #pragma unroll
        for (int mk = 1; mk < 16; mk <<= 1) {
            s[j] += __shfl_xor(s[j], mk);
            sq[j] += __shfl_xor(sq[j], mk);
        }
    }
    float mu[4], rs[4];
    #pragma unroll
    for (int j = 0; j < 4; ++j) {
        mu[j] = s[j] * (1.0f / 1024.0f);
        const float var = sq[j] * (1.0f / 1024.0f) - mu[j] * mu[j];
        rs[j] = rsqrtf(var + 1e-5f);
    }

    short* trw = &tr[wave][0];
    const int rdr = lane >> 3;        // 0..7
    const int c0 = (lane & 7) * 8;    // 0..56
    #pragma unroll
    for (int h = 0; h < 16; ++h) {
        #pragma unroll
        for (int n = 0; n < 4; ++n) {
            const float lw = lnw[h * 64 + n * 16 + r16];
            const float lb = lnb[h * 64 + n * 16 + r16];
            #pragma unroll
            for (int j = 0; j < 4; ++j) {
                const float v = bf2f(keep[h][n >> 1][(n & 1) * 4 + j]);
                const float val = (v - mu[j]) * rs[j] * lw + lb;
                trw[(g * 4 + j) * 64 + ((n ^ g) * 16 + r16)] = f2bf(val);
            }
        }
        #pragma unroll
        for (int p = 0; p < 2; ++p) {
            const int r = rdr + p * 8;
            const s16x8 t = *(const s16x8*)&trw[r * 64 + (((c0 >> 4) ^ (r >> 2)) * 16) + (c0 & 15)];
            const s16x8 uu = *(const s16x8*)(ub + (rowB + r) * 1024 + h * 64 + c0);
            s16x8 o;
            #pragma unroll
            for (int e = 0; e < 8; ++e)
                o[e] = f2bf(bf2f(t[e]) * bf2f(uu[e]));
            *(s16x8*)(yb + (rowB + r) * 1024 + h * 64 + c0) = o;
        }
    }
}

extern "C" void kernel_launch(void* const* d_in, const int* in_sizes, int n_in,
                              void* d_out, int out_size, void* d_ws, size_t ws_size,
                              hipStream_t stream) {
    (void)in_sizes; (void)n_in; (void)out_size;
    const float* query = (const float*)d_in[0];
    const float* Wq = (const float*)d_in[1];
    const float* bq = (const float*)d_in[2];
    const float* Wk = (const float*)d_in[3];
    const float* bk = (const float*)d_in[4];
    const float* Wv = (const float*)d_in[5];
    const float* bv = (const float*)d_in[6];
    const float* Wu = (const float*)d_in[7];
    const float* bu = (const float*)d_in[8];
    const float* Wo = (const float*)d_in[9];
    const float* bo = (const float*)d_in[10];
    const float* lnw = (const float*)d_in[11];
    const float* lnb = (const float*)d_in[12];
    float* out = (float*)d_out;
    char* ws = (char*)d_ws;
    if (ws_size < 380129280u) return;  // uses < 362.5 MiB

    short* Xb   = (short*)(ws);                    // 64 MiB  (later aliased by yb)
    short* Wcat = (short*)(ws + 67108864);         // 10 MiB
    float* bcat = (float*)(ws + 77594624);         // 20 KiB
    short* qb   = (short*)(ws + 77615104);         // 64 MiB
    short* ktb  = (short*)(ws + 144723968);        // 64 MiB
    short* vtb  = (short*)(ws + 211832832);        // 64 MiB
    short* ub   = (short*)(ws + 278941696);        // 64 MiB
    float* kvp  = (float*)(ws + 346050560);        // 8 MiB
    short* kvt  = (short*)(ws + 379604992);        // 512 KiB
    short* yb   = Xb;                              // 64 MiB over dead Xb

    hipFuncSetAttribute(reinterpret_cast<const void*>(&gemm8<0>),
                        hipFuncAttributeMaxDynamicSharedMemorySize, 131072);
    hipFuncSetAttribute(reinterpret_cast<const void*>(&gemm8<1>),
                        hipFuncAttributeMaxDynamicSharedMemorySize, 131072);

    prep<<<3348, 256, 0, stream>>>(query, Xb, Wq, Wk, Wv, Wu, Wo, Wcat,
                                   bq, bk, bv, bu, bo, bcat);
    gemm8<0><<<2048, 512, 131072, stream>>>(Xb, Wcat, bcat, qb, ktb, vtb, ub, nullptr);
    kv_partial<<<dim3(8, 64), 256, 0, stream>>>(ktb, vtb, kvp);
    kv_reduce<<<512, 256, 0, stream>>>(kvp, kvt);
    qkv_ln<<<512, 256, 0, stream>>>(qb, kvt, ub, lnw, lnb, yb);
    gemm8<1><<<512, 512, 131072, stream>>>(yb, Wcat + (size_t)4096 * 1024, bcat + 4096,
                                           nullptr, nullptr, nullptr, nullptr, out);
}

// Round 12
// 538.333 us; speedup vs baseline: 1.0805x; 1.0805x over previous
//
#include <hip/hip_runtime.h>

#define M_TOT 32768  // B*N

typedef float f32x4 __attribute__((ext_vector_type(4)));
typedef short s16x8 __attribute__((ext_vector_type(8)));

#define AS1(p) ((__attribute__((address_space(1))) void*)(p))
#define AS3(p) ((__attribute__((address_space(3))) void*)(p))

#define BARRIER() asm volatile("s_barrier" ::: "memory")
#define VMCNT4() asm volatile("s_waitcnt vmcnt(4)" ::: "memory")
#define VMCNT2() asm volatile("s_waitcnt vmcnt(2)" ::: "memory")
#define VMCNT0() asm volatile("s_waitcnt vmcnt(0)" ::: "memory")

__device__ __forceinline__ short f2bf(float f) {
    unsigned u = __builtin_bit_cast(unsigned, f);
    u += 0x7fffu + ((u >> 16) & 1u);
    return (short)(u >> 16);
}
__device__ __forceinline__ float bf2f(short s) {
    unsigned u = ((unsigned)(unsigned short)s) << 16;
    return __builtin_bit_cast(float, u);
}

// ---- merged prep: conv_x (blocks 0..2047) + conv_w transpose (2048..3327) + bias (3328..3347) ----
__global__ __launch_bounds__(256) void prep(const float* __restrict__ x, short* __restrict__ y,
                                            const float* __restrict__ Wq, const float* __restrict__ Wk,
                                            const float* __restrict__ Wv, const float* __restrict__ Wu,
                                            const float* __restrict__ Wo, short* __restrict__ Wcat,
                                            const float* __restrict__ bq, const float* __restrict__ bk,
                                            const float* __restrict__ bv, const float* __restrict__ bu,
                                            const float* __restrict__ bo, float* __restrict__ bcat) {
    __shared__ float t[64][65];
    const int blk = blockIdx.x;
    if (blk < 2048) {
        const size_t nchunk = (size_t)M_TOT * 1024 / 8;
        const size_t stride = (size_t)2048 * 256;
        for (size_t c = (size_t)blk * 256 + threadIdx.x; c < nchunk; c += stride) {
            const float4* src = (const float4*)(x + c * 8);
            float4 a = src[0], b = src[1];
            s16x8 r;
            r[0] = f2bf(a.x); r[1] = f2bf(a.y); r[2] = f2bf(a.z); r[3] = f2bf(a.w);
            r[4] = f2bf(b.x); r[5] = f2bf(b.y); r[6] = f2bf(b.z); r[7] = f2bf(b.w);
            *(s16x8*)(y + c * 8) = r;
        }
    } else if (blk < 3328) {
        const int b = blk - 2048;           // 0..1279
        const int mat = b >> 8;             // 0..4
        const int kt = (b >> 4) & 15, nt = b & 15;
        const int k0 = kt << 6, n0 = nt << 6;
        const float* W = (mat == 0) ? Wq : (mat == 1) ? Wk : (mat == 2) ? Wv
                       : (mat == 3) ? Wu : Wo;
        const int rr = threadIdx.x >> 4;    // 0..15
        const int cc = threadIdx.x & 15;    // 0..15
        #pragma unroll
        for (int p = 0; p < 4; ++p) {
            const int row = p * 16 + rr;
            const float4 v = *(const float4*)(W + (size_t)(k0 + row) * 1024 + n0 + cc * 4);
            t[row][cc * 4 + 0] = v.x; t[row][cc * 4 + 1] = v.y;
            t[row][cc * 4 + 2] = v.z; t[row][cc * 4 + 3] = v.w;
        }
        __syncthreads();
        #pragma unroll
        for (int p = 0; p < 4; ++p) {
            const int nr = p * 16 + rr;
            short4 r;
            r.x = f2bf(t[cc * 4 + 0][nr]); r.y = f2bf(t[cc * 4 + 1][nr]);
            r.z = f2bf(t[cc * 4 + 2][nr]); r.w = f2bf(t[cc * 4 + 3][nr]);
            *(short4*)(Wcat + (size_t)(mat * 1024 + n0 + nr) * 1024 + k0 + cc * 4) = r;
        }
    } else {
        const int i = (blk - 3328) * 256 + threadIdx.x;  // < 5120
        const float* b = (i < 1024) ? bq : (i < 2048) ? bk : (i < 3072) ? bv
                       : (i < 4096) ? bu : bo;
        bcat[i] = b[i & 1023];
    }
}

// ---- 256x256 GEMM, BK=64, 2 LDS buffers, 2 free-running windows/K-tile (r5 best, FROZEN) ----
template <int MODE>
__global__ __launch_bounds__(512, 2) void gemm8(
        const short* __restrict__ A, const short* __restrict__ W,
        const float* __restrict__ bias,
        short* __restrict__ qb, short* __restrict__ ktb,
        short* __restrict__ vtb, short* __restrict__ ub,
        float* __restrict__ outb) {
    extern __shared__ char lds[];
    const int tid = threadIdx.x;
    const int wave = tid >> 6, lane = tid & 63;
    const int r16 = lane & 15, g = lane >> 4;
    const int moff = (wave >> 2) << 7;  // 0 / 128
    const int noff = (wave & 3) << 6;   // 0 / 64 / 128 / 192

    const int nwg = (MODE == 0) ? 2048 : 512;
    const int NB = (MODE == 0) ? 16 : 4;
    const int bid = blockIdx.x;
    const int swz = (bid & 7) * (nwg >> 3) + (bid >> 3);  // XCD-chunked (nwg%8==0)
    const int mblk = swz / NB, nblk = swz % NB;           // M-outer: XCDs own disjoint A-slices
    const int row0 = mblk << 8, col0 = nblk << 8;

    // ds_read swizzled chunk offsets (lane-constant)
    const int rswz = r16 & 7;
    const int ck0 = (g ^ rswz) << 4;
    const int ck1 = ((4 + g) ^ rswz) << 4;
    const int rowbA = (moff + r16) << 7;
    const int rowbB = (noff + r16) << 7;

    // staging source (lane-constant): row-in-inst = wave*8 + (lane>>3), chunk pre-swizzled
    const char* baseA = (const char*)A + (size_t)(row0 + wave * 8 + (lane >> 3)) * 2048
                        + (((lane & 7) ^ ((lane >> 3) & 7)) << 4);
    const char* baseB = (const char*)W + (size_t)(col0 + wave * 8 + (lane >> 3)) * 2048
                        + (((lane & 7) ^ ((lane >> 3) & 7)) << 4);

#define STG(BASE, J, T, DST)                                                   \
    __builtin_amdgcn_global_load_lds(                                          \
        AS1((BASE) + (size_t)(J) * 131072 + (size_t)(T) * 128),                \
        AS3((DST) + (J) * 8192 + wave * 1024), 16, 0, 0)

#define RDA(V, M, BUFA) {                                                      \
    (V)[0] = *(const s16x8*)((BUFA) + rowbA + (M) * 2048 + ck0);               \
    (V)[1] = *(const s16x8*)((BUFA) + rowbA + (M) * 2048 + ck1); }

#define RDB(V, N, BUFB) {                                                      \
    (V)[0] = *(const s16x8*)((BUFB) + rowbB + (N) * 2048 + ck0);               \
    (V)[1] = *(const s16x8*)((BUFB) + rowbB + (N) * 2048 + ck1); }

#define MF16(P, A0, A1)                                                        \
    _Pragma("unroll") for (int kk = 0; kk < 2; ++kk)                           \
        _Pragma("unroll") for (int n = 0; n < 4; ++n) {                        \
            acc[2*(P)][n]   = __builtin_amdgcn_mfma_f32_16x16x32_bf16((A0)[kk], bfr[n][kk], acc[2*(P)][n], 0, 0, 0);   \
            acc[2*(P)+1][n] = __builtin_amdgcn_mfma_f32_16x16x32_bf16((A1)[kk], bfr[n][kk], acc[2*(P)+1][n], 0, 0, 0); \
        }

#define TILE(T, DOSTAGE, TRmid, TRend) {                                       \
    char* bA_ = lds + ((T) & 1) * 65536; char* bB_ = bA_ + 32768;              \
    char* sA_ = lds + (((T) + 1) & 1) * 65536; char* sB_ = sA_ + 32768;        \
    s16x8 a0[2], a1[2], a2[2], a3[2];                                          \
    if (DOSTAGE) { STG(baseB, 0, (T) + 1, sB_); STG(baseB, 1, (T) + 1, sB_);   \
                   STG(baseB, 2, (T) + 1, sB_); STG(baseB, 3, (T) + 1, sB_); } \
    _Pragma("unroll") for (int n = 0; n < 4; ++n) RDB(bfr[n], n, bB_);         \
    RDA(a0, 0, bA_); RDA(a1, 1, bA_); RDA(a2, 2, bA_); RDA(a3, 3, bA_);        \
    __builtin_amdgcn_s_setprio(1);                                             \
    MF16(0, a0, a1); MF16(1, a2, a3);                                          \
    __builtin_amdgcn_s_setprio(0);                                             \
    TRmid; BARRIER();                                                          \
    if (DOSTAGE) { STG(baseA, 0, (T) + 1, sA_); STG(baseA, 2, (T) + 1, sA_);   \
                   STG(baseA, 1, (T) + 1, sA_); STG(baseA, 3, (T) + 1, sA_); } \
    RDA(a0, 4, bA_); RDA(a1, 5, bA_); RDA(a2, 6, bA_); RDA(a3, 7, bA_);        \
    __builtin_amdgcn_s_setprio(1);                                             \
    MF16(2, a0, a1); MF16(3, a2, a3);                                          \
    __builtin_amdgcn_s_setprio(0);                                             \
    TRend; BARRIER(); }

    f32x4 acc[8][4] = {};
    s16x8 bfr[4][2];

    // prologue: stage tile 0 in steady-state issue order, keep A1,A3 in flight
    STG(baseB, 0, 0, lds + 32768); STG(baseB, 1, 0, lds + 32768);
    STG(baseB, 2, 0, lds + 32768); STG(baseB, 3, 0, lds + 32768);
    STG(baseA, 0, 0, lds);         STG(baseA, 2, 0, lds);
    STG(baseA, 1, 0, lds);         STG(baseA, 3, 0, lds);
    VMCNT2();
    BARRIER();

    #pragma unroll 1
    for (int t = 0; t < 15; ++t) TILE(t, true, VMCNT4(), VMCNT2());
    TILE(15, false, VMCNT0(), (void)0);

    // ---- epilogue ----
    const int rj = (lane >> 4) << 2;
    if (MODE == 1) {
        #pragma unroll
        for (int n = 0; n < 4; ++n) {
            const int gn = col0 + noff + n * 16 + r16;
            const float bv = bias[gn];
            #pragma unroll
            for (int m = 0; m < 8; ++m) {
                const int gm0 = row0 + moff + m * 16 + rj;
                #pragma unroll
                for (int j = 0; j < 4; ++j)
                    outb[(size_t)(gm0 + j) * 1024 + gn] = acc[m][n][j] + bv;
            }
        }
    } else {
        const int seg = col0 >> 10;  // block-uniform (256-col block within one 1024 seg)
        if (seg == 0 || seg == 3) {
            short* dst = (seg == 0) ? qb : ub;
            const bool do_relu = (seg == 0);
            #pragma unroll
            for (int n = 0; n < 4; ++n) {
                const int gn = col0 + noff + n * 16 + r16;
                const int f = gn & 1023;
                const float bv = bias[gn];
                #pragma unroll
                for (int m = 0; m < 8; ++m) {
                    const int gm0 = row0 + moff + m * 16 + rj;
                    #pragma unroll
                    for (int j = 0; j < 4; ++j) {
                        float val = acc[m][n][j] + bv;
                        if (do_relu) val = fmaxf(val, 0.0f);
                        dst[(size_t)(gm0 + j) * 1024 + f] = f2bf(val);
                    }
                }
            }
        } else {
            short* dst = (seg == 1) ? ktb : vtb;
            const bool do_relu = (seg == 1);
            #pragma unroll
            for (int n = 0; n < 4; ++n) {
                const int gn = col0 + noff + n * 16 + r16;
                const int hd = gn & 1023;  // h*64+d
                const float bv = bias[gn];
                #pragma unroll
                for (int m = 0; m < 8; ++m) {
                    const int gm0 = row0 + moff + m * 16 + rj;  // token, multiple of 4
                    const int b = gm0 >> 13;
                    const int ntok = gm0 & 8191;
                    float v0 = acc[m][n][0] + bv, v1 = acc[m][n][1] + bv;
                    float v2 = acc[m][n][2] + bv, v3 = acc[m][n][3] + bv;
                    if (do_relu) {
                        v0 = fmaxf(v0, 0.0f); v1 = fmaxf(v1, 0.0f);
                        v2 = fmaxf(v2, 0.0f); v3 = fmaxf(v3, 0.0f);
                    }
                    short4 pk;
                    pk.x = f2bf(v0); pk.y = f2bf(v1); pk.z = f2bf(v2); pk.w = f2bf(v3);
                    *(short4*)(dst + ((size_t)(b * 1024 + hd)) * 8192 + ntok) = pk;
                }
            }
        }
    }
#undef TILE
#undef MF16
#undef RDB
#undef RDA
#undef STG
}

// ---- kv partials: 4-wave block per (slice, bh); 1024 tokens; LDS cross-wave reduce ----
__global__ __launch_bounds__(256) void kv_partial(const short* __restrict__ ktb,
                                                  const short* __restrict__ vtb,
                                                  float* __restrict__ kvp) {
    __shared__ float red[4][4096];  // 64 KB
    const int slice = blockIdx.x;  // 0..7
    const int bh = blockIdx.y;     // 0..63
    const int wave = threadIdx.x >> 6, lane = threadIdx.x & 63;
    const int r16 = lane & 15;
    const short* kb = ktb + (size_t)bh * 64 * 8192;
    const short* vb = vtb + (size_t)bh * 64 * 8192;
    const int n0 = (slice << 10) + (wave << 8);
    f32x4 acc[4][4] = {};
    for (int s = 0; s < 8; ++s) {
        const int nk = n0 + (s << 5) + ((lane >> 4) << 3);
        s16x8 af[4], bf[4];
        #pragma unroll
        for (int m = 0; m < 4; ++m) af[m] = *(const s16x8*)(kb + (size_t)(m * 16 + r16) * 8192 + nk);
        #pragma unroll
        for (int n = 0; n < 4; ++n) bf[n] = *(const s16x8*)(vb + (size_t)(n * 16 + r16) * 8192 + nk);
        #pragma unroll
        for (int m = 0; m < 4; ++m)
            #pragma unroll
            for (int n = 0; n < 4; ++n)
                acc[m][n] = __builtin_amdgcn_mfma_f32_16x16x32_bf16(af[m], bf[n], acc[m][n], 0, 0, 0);
    }
    const int rj = (lane >> 4) << 2;
    #pragma unroll
    for (int m = 0; m < 4; ++m)
        #pragma unroll
        for (int n = 0; n < 4; ++n)
            #pragma unroll
            for (int j = 0; j < 4; ++j)
                red[wave][(m * 16 + rj + j) * 64 + n * 16 + r16] = acc[m][n][j];
    __syncthreads();
    float* dst = kvp + ((size_t)slice * 64 + bh) * 4096;
    const int i0 = threadIdx.x * 16;
    #pragma unroll
    for (int e = 0; e < 16; e += 4) {
        f32x4 a0 = *(const f32x4*)&red[0][i0 + e];
        f32x4 a1 = *(const f32x4*)&red[1][i0 + e];
        f32x4 a2 = *(const f32x4*)&red[2][i0 + e];
        f32x4 a3 = *(const f32x4*)&red[3][i0 + e];
        *(f32x4*)&dst[i0 + e] = (a0 + a1) + (a2 + a3);
    }
}

// ---- reduce 8 kv partials, abs-clamp, store transposed bf16 kv_t[bh][e][d] ----
__global__ void kv_reduce(const float* __restrict__ kvp, short* __restrict__ kvt) {
    const int bh = blockIdx.x;
    for (int i = threadIdx.x; i < 4096; i += 256) {
        float s = 0.0f;
        #pragma unroll
        for (int sl = 0; sl < 8; ++sl)
            s += kvp[((size_t)sl * 64 + bh) * 4096 + i];
        float a = fabsf(s);
        float cmag = fminf(fmaxf(a, 0.01f), 100.0f);
        float r = (s > 0.0f) ? cmag : ((s < 0.0f) ? -cmag : 0.0f);
        const int d = i >> 6, e = i & 63;
        kvt[(size_t)bh * 4096 + e * 64 + d] = f2bf(r);
    }
}

// ---- fused o = q @ kv -> LayerNorm -> * u -> y (bf16), two-pass (r5 best) ----
__global__ __launch_bounds__(256) void qkv_ln(const short* __restrict__ qb,
                                              const short* __restrict__ kvt,
                                              const short* __restrict__ ub,
                                              const float* __restrict__ lnw,
                                              const float* __restrict__ lnb,
                                              short* __restrict__ yb) {
    __shared__ short tr[4][1024];  // 2 KB per wave
    const int wave = threadIdx.x >> 6, lane = threadIdx.x & 63;
    const int r16 = lane & 15, g = lane >> 4;
    const size_t rowB = (size_t)blockIdx.x * 64 + wave * 16;
    const int bh0 = (int)((rowB >> 13) << 4);
    const short* qrow = qb + (rowB + r16) * 1024 + g * 8;

    float s[4] = {0, 0, 0, 0}, sq[4] = {0, 0, 0, 0};
    for (int h = 0; h < 16; ++h) {
        const short* kvb = kvt + (size_t)(bh0 + h) * 4096 + g * 8;
        f32x4 a4[4] = {};
        #pragma unroll
        for (int kk = 0; kk < 2; ++kk) {
            const s16x8 af = *(const s16x8*)(qrow + h * 64 + kk * 32);
            #pragma unroll
            for (int n = 0; n < 4; ++n) {
                const s16x8 bf = *(const s16x8*)(kvb + (n * 16 + r16) * 64 + kk * 32);
                a4[n] = __builtin_amdgcn_mfma_f32_16x16x32_bf16(af, bf, a4[n], 0, 0, 0);
            }
        }
        #pragma unroll
        for (int n = 0; n < 4; ++n)
            #pragma unroll
            for (int j = 0; j < 4; ++j) {
                const float v = a4[n][j];
                s[j] += v; sq[j] += v * v;
            }
    }
    #pragma unroll
    for (int j = 0; j < 4; ++j) {
        #pragma unroll
        for (int mk = 1; mk < 16; mk <<= 1) {
            s[j] += __shfl_xor(s[j], mk);
            sq[j] += __shfl_xor(sq[j], mk);
        }
    }
    float mu[4], rs[4];
    #pragma unroll
    for (int j = 0; j < 4; ++j) {
        mu[j] = s[j] * (1.0f / 1024.0f);
        const float var = sq[j] * (1.0f / 1024.0f) - mu[j] * mu[j];
        rs[j] = rsqrtf(var + 1e-5f);
    }

    short* trw = &tr[wave][0];
    const int rdr = lane >> 3;        // 0..7
    const int c0 = (lane & 7) * 8;    // 0..56
    for (int h = 0; h < 16; ++h) {
        const short* kvb = kvt + (size_t)(bh0 + h) * 4096 + g * 8;
        f32x4 a4[4] = {};
        #pragma unroll
        for (int kk = 0; kk < 2; ++kk) {
            const s16x8 af = *(const s16x8*)(qrow + h * 64 + kk * 32);
            #pragma unroll
            for (int n = 0; n < 4; ++n) {
                const s16x8 bf = *(const s16x8*)(kvb + (n * 16 + r16) * 64 + kk * 32);
                a4[n] = __builtin_amdgcn_mfma_f32_16x16x32_bf16(af, bf, a4[n], 0, 0, 0);
            }
        }
        #pragma unroll
        for (int n = 0; n < 4; ++n) {
            const float lw = lnw[h * 64 + n * 16 + r16];
            const float lb = lnb[h * 64 + n * 16 + r16];
            #pragma unroll
            for (int j = 0; j < 4; ++j) {
                const float val = (a4[n][j] - mu[j]) * rs[j] * lw + lb;
                trw[(g * 4 + j) * 64 + ((n ^ g) * 16 + r16)] = f2bf(val);
            }
        }
        #pragma unroll
        for (int p = 0; p < 2; ++p) {
            const int r = rdr + p * 8;
            const s16x8 t = *(const s16x8*)&trw[r * 64 + (((c0 >> 4) ^ (r >> 2)) * 16) + (c0 & 15)];
            const s16x8 uu = *(const s16x8*)(ub + (rowB + r) * 1024 + h * 64 + c0);
            s16x8 o;
            #pragma unroll
            for (int e = 0; e < 8; ++e)
                o[e] = f2bf(bf2f(t[e]) * bf2f(uu[e]));
            *(s16x8*)(yb + (rowB + r) * 1024 + h * 64 + c0) = o;
        }
    }
}

extern "C" void kernel_launch(void* const* d_in, const int* in_sizes, int n_in,
                              void* d_out, int out_size, void* d_ws, size_t ws_size,
                              hipStream_t stream) {
    (void)in_sizes; (void)n_in; (void)out_size;
    const float* query = (const float*)d_in[0];
    const float* Wq = (const float*)d_in[1];
    const float* bq = (const float*)d_in[2];
    const float* Wk = (const float*)d_in[3];
    const float* bk = (const float*)d_in[4];
    const float* Wv = (const float*)d_in[5];
    const float* bv = (const float*)d_in[6];
    const float* Wu = (const float*)d_in[7];
    const float* bu = (const float*)d_in[8];
    const float* Wo = (const float*)d_in[9];
    const float* bo = (const float*)d_in[10];
    const float* lnw = (const float*)d_in[11];
    const float* lnb = (const float*)d_in[12];
    float* out = (float*)d_out;
    char* ws = (char*)d_ws;
    if (ws_size < 380129280u) return;  // uses < 362.5 MiB

    short* Xb   = (short*)(ws);                    // 64 MiB  (later aliased by yb)
    short* Wcat = (short*)(ws + 67108864);         // 10 MiB
    float* bcat = (float*)(ws + 77594624);         // 20 KiB
    short* qb   = (short*)(ws + 77615104);         // 64 MiB
    short* ktb  = (short*)(ws + 144723968);        // 64 MiB
    short* vtb  = (short*)(ws + 211832832);        // 64 MiB
    short* ub   = (short*)(ws + 278941696);        // 64 MiB
    float* kvp  = (float*)(ws + 346050560);        // 8 MiB
    short* kvt  = (short*)(ws + 379604992);        // 512 KiB
    short* yb   = Xb;                              // 64 MiB over dead Xb

    hipFuncSetAttribute(reinterpret_cast<const void*>(&gemm8<0>),
                        hipFuncAttributeMaxDynamicSharedMemorySize, 131072);
    hipFuncSetAttribute(reinterpret_cast<const void*>(&gemm8<1>),
                        hipFuncAttributeMaxDynamicSharedMemorySize, 131072);

    prep<<<3348, 256, 0, stream>>>(query, Xb, Wq, Wk, Wv, Wu, Wo, Wcat,
                                   bq, bk, bv, bu, bo, bcat);
    gemm8<0><<<2048, 512, 131072, stream>>>(Xb, Wcat, bcat, qb, ktb, vtb, ub, nullptr);
    kv_partial<<<dim3(8, 64), 256, 0, stream>>>(ktb, vtb, kvp);
    kv_reduce<<<64, 256, 0, stream>>>(kvp, kvt);
    qkv_ln<<<512, 256, 0, stream>>>(qb, kvt, ub, lnw, lnb, yb);
    gemm8<1><<<512, 512, 131072, stream>>>(yb, Wcat + (size_t)4096 * 1024, bcat + 4096,
                                           nullptr, nullptr, nullptr, nullptr, out);
}

// Round 13
// 532.882 us; speedup vs baseline: 1.0915x; 1.0102x over previous
//
#include <hip/hip_runtime.h>

#define M_TOT 32768  // B*N

typedef float f32x4 __attribute__((ext_vector_type(4)));
typedef short s16x8 __attribute__((ext_vector_type(8)));

#define AS1(p) ((__attribute__((address_space(1))) void*)(p))
#define AS3(p) ((__attribute__((address_space(3))) void*)(p))

#define BARRIER() asm volatile("s_barrier" ::: "memory")
#define VMCNT4() asm volatile("s_waitcnt vmcnt(4)" ::: "memory")
#define VMCNT2() asm volatile("s_waitcnt vmcnt(2)" ::: "memory")
#define VMCNT0() asm volatile("s_waitcnt vmcnt(0)" ::: "memory")

__device__ __forceinline__ short f2bf(float f) {
    unsigned u = __builtin_bit_cast(unsigned, f);
    u += 0x7fffu + ((u >> 16) & 1u);
    return (short)(u >> 16);
}
__device__ __forceinline__ float bf2f(short s) {
    unsigned u = ((unsigned)(unsigned short)s) << 16;
    return __builtin_bit_cast(float, u);
}

// ---- merged prep: conv_x (blocks 0..2047) + conv_w transpose (2048..3327) + bias (3328..3347) ----
__global__ __launch_bounds__(256) void prep(const float* __restrict__ x, short* __restrict__ y,
                                            const float* __restrict__ Wq, const float* __restrict__ Wk,
                                            const float* __restrict__ Wv, const float* __restrict__ Wu,
                                            const float* __restrict__ Wo, short* __restrict__ Wcat,
                                            const float* __restrict__ bq, const float* __restrict__ bk,
                                            const float* __restrict__ bv, const float* __restrict__ bu,
                                            const float* __restrict__ bo, float* __restrict__ bcat) {
    __shared__ float t[64][65];
    const int blk = blockIdx.x;
    if (blk < 2048) {
        const size_t nchunk = (size_t)M_TOT * 1024 / 8;
        const size_t stride = (size_t)2048 * 256;
        for (size_t c = (size_t)blk * 256 + threadIdx.x; c < nchunk; c += stride) {
            const float4* src = (const float4*)(x + c * 8);
            float4 a = src[0], b = src[1];
            s16x8 r;
            r[0] = f2bf(a.x); r[1] = f2bf(a.y); r[2] = f2bf(a.z); r[3] = f2bf(a.w);
            r[4] = f2bf(b.x); r[5] = f2bf(b.y); r[6] = f2bf(b.z); r[7] = f2bf(b.w);
            *(s16x8*)(y + c * 8) = r;
        }
    } else if (blk < 3328) {
        const int b = blk - 2048;           // 0..1279
        const int mat = b >> 8;             // 0..4
        const int kt = (b >> 4) & 15, nt = b & 15;
        const int k0 = kt << 6, n0 = nt << 6;
        const float* W = (mat == 0) ? Wq : (mat == 1) ? Wk : (mat == 2) ? Wv
                       : (mat == 3) ? Wu : Wo;
        const int rr = threadIdx.x >> 4;    // 0..15
        const int cc = threadIdx.x & 15;    // 0..15
        #pragma unroll
        for (int p = 0; p < 4; ++p) {
            const int row = p * 16 + rr;
            const float4 v = *(const float4*)(W + (size_t)(k0 + row) * 1024 + n0 + cc * 4);
            t[row][cc * 4 + 0] = v.x; t[row][cc * 4 + 1] = v.y;
            t[row][cc * 4 + 2] = v.z; t[row][cc * 4 + 3] = v.w;
        }
        __syncthreads();
        #pragma unroll
        for (int p = 0; p < 4; ++p) {
            const int nr = p * 16 + rr;
            short4 r;
            r.x = f2bf(t[cc * 4 + 0][nr]); r.y = f2bf(t[cc * 4 + 1][nr]);
            r.z = f2bf(t[cc * 4 + 2][nr]); r.w = f2bf(t[cc * 4 + 3][nr]);
            *(short4*)(Wcat + (size_t)(mat * 1024 + n0 + nr) * 1024 + k0 + cc * 4) = r;
        }
    } else {
        const int i = (blk - 3328) * 256 + threadIdx.x;  // < 5120
        const float* b = (i < 1024) ? bq : (i < 2048) ? bk : (i < 3072) ? bv
                       : (i < 4096) ? bu : bo;
        bcat[i] = b[i & 1023];
    }
}

// ---- 256x256 GEMM, BK=64, 2 LDS buffers, 2 free-running windows/K-tile (r5 best, FROZEN) ----
template <int MODE>
__global__ __launch_bounds__(512, 2) void gemm8(
        const short* __restrict__ A, const short* __restrict__ W,
        const float* __restrict__ bias,
        short* __restrict__ qb, short* __restrict__ ktb,
        short* __restrict__ vtb, short* __restrict__ ub,
        float* __restrict__ outb) {
    extern __shared__ char lds[];
    const int tid = threadIdx.x;
    const int wave = tid >> 6, lane = tid & 63;
    const int r16 = lane & 15, g = lane >> 4;
    const int moff = (wave >> 2) << 7;  // 0 / 128
    const int noff = (wave & 3) << 6;   // 0 / 64 / 128 / 192

    const int nwg = (MODE == 0) ? 2048 : 512;
    const int NB = (MODE == 0) ? 16 : 4;
    const int bid = blockIdx.x;
    const int swz = (bid & 7) * (nwg >> 3) + (bid >> 3);  // XCD-chunked (nwg%8==0)
    const int mblk = swz / NB, nblk = swz % NB;           // M-outer: XCDs own disjoint A-slices
    const int row0 = mblk << 8, col0 = nblk << 8;

    // ds_read swizzled chunk offsets (lane-constant)
    const int rswz = r16 & 7;
    const int ck0 = (g ^ rswz) << 4;
    const int ck1 = ((4 + g) ^ rswz) << 4;
    const int rowbA = (moff + r16) << 7;
    const int rowbB = (noff + r16) << 7;

    // staging source (lane-constant): row-in-inst = wave*8 + (lane>>3), chunk pre-swizzled
    const char* baseA = (const char*)A + (size_t)(row0 + wave * 8 + (lane >> 3)) * 2048
                        + (((lane & 7) ^ ((lane >> 3) & 7)) << 4);
    const char* baseB = (const char*)W + (size_t)(col0 + wave * 8 + (lane >> 3)) * 2048
                        + (((lane & 7) ^ ((lane >> 3) & 7)) << 4);

#define STG(BASE, J, T, DST)                                                   \
    __builtin_amdgcn_global_load_lds(                                          \
        AS1((BASE) + (size_t)(J) * 131072 + (size_t)(T) * 128),                \
        AS3((DST) + (J) * 8192 + wave * 1024), 16, 0, 0)

#define RDA(V, M, BUFA) {                                                      \
    (V)[0] = *(const s16x8*)((BUFA) + rowbA + (M) * 2048 + ck0);               \
    (V)[1] = *(const s16x8*)((BUFA) + rowbA + (M) * 2048 + ck1); }

#define RDB(V, N, BUFB) {                                                      \
    (V)[0] = *(const s16x8*)((BUFB) + rowbB + (N) * 2048 + ck0);               \
    (V)[1] = *(const s16x8*)((BUFB) + rowbB + (N) * 2048 + ck1); }

#define MF16(P, A0, A1)                                                        \
    _Pragma("unroll") for (int kk = 0; kk < 2; ++kk)                           \
        _Pragma("unroll") for (int n = 0; n < 4; ++n) {                        \
            acc[2*(P)][n]   = __builtin_amdgcn_mfma_f32_16x16x32_bf16((A0)[kk], bfr[n][kk], acc[2*(P)][n], 0, 0, 0);   \
            acc[2*(P)+1][n] = __builtin_amdgcn_mfma_f32_16x16x32_bf16((A1)[kk], bfr[n][kk], acc[2*(P)+1][n], 0, 0, 0); \
        }

#define TILE(T, DOSTAGE, TRmid, TRend) {                                       \
    char* bA_ = lds + ((T) & 1) * 65536; char* bB_ = bA_ + 32768;              \
    char* sA_ = lds + (((T) + 1) & 1) * 65536; char* sB_ = sA_ + 32768;        \
    s16x8 a0[2], a1[2], a2[2], a3[2];                                          \
    if (DOSTAGE) { STG(baseB, 0, (T) + 1, sB_); STG(baseB, 1, (T) + 1, sB_);   \
                   STG(baseB, 2, (T) + 1, sB_); STG(baseB, 3, (T) + 1, sB_); } \
    _Pragma("unroll") for (int n = 0; n < 4; ++n) RDB(bfr[n], n, bB_);         \
    RDA(a0, 0, bA_); RDA(a1, 1, bA_); RDA(a2, 2, bA_); RDA(a3, 3, bA_);        \
    __builtin_amdgcn_s_setprio(1);                                             \
    MF16(0, a0, a1); MF16(1, a2, a3);                                          \
    __builtin_amdgcn_s_setprio(0);                                             \
    TRmid; BARRIER();                                                          \
    if (DOSTAGE) { STG(baseA, 0, (T) + 1, sA_); STG(baseA, 2, (T) + 1, sA_);   \
                   STG(baseA, 1, (T) + 1, sA_); STG(baseA, 3, (T) + 1, sA_); } \
    RDA(a0, 4, bA_); RDA(a1, 5, bA_); RDA(a2, 6, bA_); RDA(a3, 7, bA_);        \
    __builtin_amdgcn_s_setprio(1);                                             \
    MF16(2, a0, a1); MF16(3, a2, a3);                                          \
    __builtin_amdgcn_s_setprio(0);                                             \
    TRend; BARRIER(); }

    f32x4 acc[8][4] = {};
    s16x8 bfr[4][2];

    // prologue: stage tile 0 in steady-state issue order, keep A1,A3 in flight
    STG(baseB, 0, 0, lds + 32768); STG(baseB, 1, 0, lds + 32768);
    STG(baseB, 2, 0, lds + 32768); STG(baseB, 3, 0, lds + 32768);
    STG(baseA, 0, 0, lds);         STG(baseA, 2, 0, lds);
    STG(baseA, 1, 0, lds);         STG(baseA, 3, 0, lds);
    VMCNT2();
    BARRIER();

    #pragma unroll 1
    for (int t = 0; t < 15; ++t) TILE(t, true, VMCNT4(), VMCNT2());
    TILE(15, false, VMCNT0(), (void)0);

    // ---- epilogue ----
    const int rj = (lane >> 4) << 2;
    if (MODE == 1) {
        #pragma unroll
        for (int n = 0; n < 4; ++n) {
            const int gn = col0 + noff + n * 16 + r16;
            const float bv = bias[gn];
            #pragma unroll
            for (int m = 0; m < 8; ++m) {
                const int gm0 = row0 + moff + m * 16 + rj;
                #pragma unroll
                for (int j = 0; j < 4; ++j)
                    outb[(size_t)(gm0 + j) * 1024 + gn] = acc[m][n][j] + bv;
            }
        }
    } else {
        const int seg = col0 >> 10;  // block-uniform (256-col block within one 1024 seg)
        if (seg == 0 || seg == 3) {
            short* dst = (seg == 0) ? qb : ub;
            const bool do_relu = (seg == 0);
            #pragma unroll
            for (int n = 0; n < 4; ++n) {
                const int gn = col0 + noff + n * 16 + r16;
                const int f = gn & 1023;
                const float bv = bias[gn];
                #pragma unroll
                for (int m = 0; m < 8; ++m) {
                    const int gm0 = row0 + moff + m * 16 + rj;
                    #pragma unroll
                    for (int j = 0; j < 4; ++j) {
                        float val = acc[m][n][j] + bv;
                        if (do_relu) val = fmaxf(val, 0.0f);
                        dst[(size_t)(gm0 + j) * 1024 + f] = f2bf(val);
                    }
                }
            }
        } else {
            short* dst = (seg == 1) ? ktb : vtb;
            const bool do_relu = (seg == 1);
            #pragma unroll
            for (int n = 0; n < 4; ++n) {
                const int gn = col0 + noff + n * 16 + r16;
                const int hd = gn & 1023;  // h*64+d
                const float bv = bias[gn];
                #pragma unroll
                for (int m = 0; m < 8; ++m) {
                    const int gm0 = row0 + moff + m * 16 + rj;  // token, multiple of 4
                    const int b = gm0 >> 13;
                    const int ntok = gm0 & 8191;
                    float v0 = acc[m][n][0] + bv, v1 = acc[m][n][1] + bv;
                    float v2 = acc[m][n][2] + bv, v3 = acc[m][n][3] + bv;
                    if (do_relu) {
                        v0 = fmaxf(v0, 0.0f); v1 = fmaxf(v1, 0.0f);
                        v2 = fmaxf(v2, 0.0f); v3 = fmaxf(v3, 0.0f);
                    }
                    short4 pk;
                    pk.x = f2bf(v0); pk.y = f2bf(v1); pk.z = f2bf(v2); pk.w = f2bf(v3);
                    *(short4*)(dst + ((size_t)(b * 1024 + hd)) * 8192 + ntok) = pk;
                }
            }
        }
    }
#undef TILE
#undef MF16
#undef RDB
#undef RDA
#undef STG
}

// ---- kv partials: 4-wave block per (slice, bh); 1024 tokens; LDS cross-wave reduce ----
__global__ __launch_bounds__(256) void kv_partial(const short* __restrict__ ktb,
                                                  const short* __restrict__ vtb,
                                                  float* __restrict__ kvp) {
    __shared__ float red[4][4096];  // 64 KB
    const int slice = blockIdx.x;  // 0..7
    const int bh = blockIdx.y;     // 0..63
    const int wave = threadIdx.x >> 6, lane = threadIdx.x & 63;
    const int r16 = lane & 15;
    const short* kb = ktb + (size_t)bh * 64 * 8192;
    const short* vb = vtb + (size_t)bh * 64 * 8192;
    const int n0 = (slice << 10) + (wave << 8);
    f32x4 acc[4][4] = {};
    for (int s = 0; s < 8; ++s) {
        const int nk = n0 + (s << 5) + ((lane >> 4) << 3);
        s16x8 af[4], bf[4];
        #pragma unroll
        for (int m = 0; m < 4; ++m) af[m] = *(const s16x8*)(kb + (size_t)(m * 16 + r16) * 8192 + nk);
        #pragma unroll
        for (int n = 0; n < 4; ++n) bf[n] = *(const s16x8*)(vb + (size_t)(n * 16 + r16) * 8192 + nk);
        #pragma unroll
        for (int m = 0; m < 4; ++m)
            #pragma unroll
            for (int n = 0; n < 4; ++n)
                acc[m][n] = __builtin_amdgcn_mfma_f32_16x16x32_bf16(af[m], bf[n], acc[m][n], 0, 0, 0);
    }
    const int rj = (lane >> 4) << 2;
    #pragma unroll
    for (int m = 0; m < 4; ++m)
        #pragma unroll
        for (int n = 0; n < 4; ++n)
            #pragma unroll
            for (int j = 0; j < 4; ++j)
                red[wave][(m * 16 + rj + j) * 64 + n * 16 + r16] = acc[m][n][j];
    __syncthreads();
    float* dst = kvp + ((size_t)slice * 64 + bh) * 4096;
    const int i0 = threadIdx.x * 16;
    #pragma unroll
    for (int e = 0; e < 16; e += 4) {
        f32x4 a0 = *(const f32x4*)&red[0][i0 + e];
        f32x4 a1 = *(const f32x4*)&red[1][i0 + e];
        f32x4 a2 = *(const f32x4*)&red[2][i0 + e];
        f32x4 a3 = *(const f32x4*)&red[3][i0 + e];
        *(f32x4*)&dst[i0 + e] = (a0 + a1) + (a2 + a3);
    }
}

// ---- reduce 8 kv partials, abs-clamp, store transposed bf16 kv_t[bh][e][d]; 512 blocks ----
__global__ void kv_reduce(const float* __restrict__ kvp, short* __restrict__ kvt) {
    const int bh = blockIdx.x >> 3;
    const int seg = blockIdx.x & 7;
    const int i = (seg << 9) + threadIdx.x * 2;
    #pragma unroll
    for (int p = 0; p < 2; ++p) {
        const int ii = i + p;
        float s = 0.0f;
        #pragma unroll
        for (int sl = 0; sl < 8; ++sl)
            s += kvp[((size_t)sl * 64 + bh) * 4096 + ii];
        float a = fabsf(s);
        float cmag = fminf(fmaxf(a, 0.01f), 100.0f);
        float r = (s > 0.0f) ? cmag : ((s < 0.0f) ? -cmag : 0.0f);
        const int d = ii >> 6, e = ii & 63;
        kvt[(size_t)bh * 4096 + e * 64 + d] = f2bf(r);
    }
}

// ---- fused o = q @ kv -> LayerNorm -> * u -> y (bf16), two-pass (r5 best) ----
__global__ __launch_bounds__(256) void qkv_ln(const short* __restrict__ qb,
                                              const short* __restrict__ kvt,
                                              const short* __restrict__ ub,
                                              const float* __restrict__ lnw,
                                              const float* __restrict__ lnb,
                                              short* __restrict__ yb) {
    __shared__ short tr[4][1024];  // 2 KB per wave
    const int wave = threadIdx.x >> 6, lane = threadIdx.x & 63;
    const int r16 = lane & 15, g = lane >> 4;
    const size_t rowB = (size_t)blockIdx.x * 64 + wave * 16;
    const int bh0 = (int)((rowB >> 13) << 4);
    const short* qrow = qb + (rowB + r16) * 1024 + g * 8;

    float s[4] = {0, 0, 0, 0}, sq[4] = {0, 0, 0, 0};
    for (int h = 0; h < 16; ++h) {
        const short* kvb = kvt + (size_t)(bh0 + h) * 4096 + g * 8;
        f32x4 a4[4] = {};
        #pragma unroll
        for (int kk = 0; kk < 2; ++kk) {
            const s16x8 af = *(const s16x8*)(qrow + h * 64 + kk * 32);
            #pragma unroll
            for (int n = 0; n < 4; ++n) {
                const s16x8 bf = *(const s16x8*)(kvb + (n * 16 + r16) * 64 + kk * 32);
                a4[n] = __builtin_amdgcn_mfma_f32_16x16x32_bf16(af, bf, a4[n], 0, 0, 0);
            }
        }
        #pragma unroll
        for (int n = 0; n < 4; ++n)
            #pragma unroll
            for (int j = 0; j < 4; ++j) {
                const float v = a4[n][j];
                s[j] += v; sq[j] += v * v;
            }
    }
    #pragma unroll
    for (int j = 0; j < 4; ++j) {
        #pragma unroll
        for (int mk = 1; mk < 16; mk <<= 1) {
            s[j] += __shfl_xor(s[j], mk);
            sq[j] += __shfl_xor(sq[j], mk);
        }
    }
    float mu[4], rs[4];
    #pragma unroll
    for (int j = 0; j < 4; ++j) {
        mu[j] = s[j] * (1.0f / 1024.0f);
        const float var = sq[j] * (1.0f / 1024.0f) - mu[j] * mu[j];
        rs[j] = rsqrtf(var + 1e-5f);
    }

    short* trw = &tr[wave][0];
    const int rdr = lane >> 3;        // 0..7
    const int c0 = (lane & 7) * 8;    // 0..56
    for (int h = 0; h < 16; ++h) {
        const short* kvb = kvt + (size_t)(bh0 + h) * 4096 + g * 8;
        f32x4 a4[4] = {};
        #pragma unroll
        for (int kk = 0; kk < 2; ++kk) {
            const s16x8 af = *(const s16x8*)(qrow + h * 64 + kk * 32);
            #pragma unroll
            for (int n = 0; n < 4; ++n) {
                const s16x8 bf = *(const s16x8*)(kvb + (n * 16 + r16) * 64 + kk * 32);
                a4[n] = __builtin_amdgcn_mfma_f32_16x16x32_bf16(af, bf, a4[n], 0, 0, 0);
            }
        }
        #pragma unroll
        for (int n = 0; n < 4; ++n) {
            const float lw = lnw[h * 64 + n * 16 + r16];
            const float lb = lnb[h * 64 + n * 16 + r16];
            #pragma unroll
            for (int j = 0; j < 4; ++j) {
                const float val = (a4[n][j] - mu[j]) * rs[j] * lw + lb;
                trw[(g * 4 + j) * 64 + ((n ^ g) * 16 + r16)] = f2bf(val);
            }
        }
        #pragma unroll
        for (int p = 0; p < 2; ++p) {
            const int r = rdr + p * 8;
            const s16x8 t = *(const s16x8*)&trw[r * 64 + (((c0 >> 4) ^ (r >> 2)) * 16) + (c0 & 15)];
            const s16x8 uu = *(const s16x8*)(ub + (rowB + r) * 1024 + h * 64 + c0);
            s16x8 o;
            #pragma unroll
            for (int e = 0; e < 8; ++e)
                o[e] = f2bf(bf2f(t[e]) * bf2f(uu[e]));
            *(s16x8*)(yb + (rowB + r) * 1024 + h * 64 + c0) = o;
        }
    }
}

extern "C" void kernel_launch(void* const* d_in, const int* in_sizes, int n_in,
                              void* d_out, int out_size, void* d_ws, size_t ws_size,
                              hipStream_t stream) {
    (void)in_sizes; (void)n_in; (void)out_size;
    const float* query = (const float*)d_in[0];
    const float* Wq = (const float*)d_in[1];
    const float* bq = (const float*)d_in[2];
    const float* Wk = (const float*)d_in[3];
    const float* bk = (const float*)d_in[4];
    const float* Wv = (const float*)d_in[5];
    const float* bv = (const float*)d_in[6];
    const float* Wu = (const float*)d_in[7];
    const float* bu = (const float*)d_in[8];
    const float* Wo = (const float*)d_in[9];
    const float* bo = (const float*)d_in[10];
    const float* lnw = (const float*)d_in[11];
    const float* lnb = (const float*)d_in[12];
    float* out = (float*)d_out;
    char* ws = (char*)d_ws;
    if (ws_size < 380129280u) return;  // uses < 362.5 MiB

    short* Xb   = (short*)(ws);                    // 64 MiB  (later aliased by yb)
    short* Wcat = (short*)(ws + 67108864);         // 10 MiB
    float* bcat = (float*)(ws + 77594624);         // 20 KiB
    short* qb   = (short*)(ws + 77615104);         // 64 MiB
    short* ktb  = (short*)(ws + 144723968);        // 64 MiB
    short* vtb  = (short*)(ws + 211832832);        // 64 MiB
    short* ub   = (short*)(ws + 278941696);        // 64 MiB
    float* kvp  = (float*)(ws + 346050560);        // 8 MiB
    short* kvt  = (short*)(ws + 379604992);        // 512 KiB
    short* yb   = Xb;                              // 64 MiB over dead Xb

    hipFuncSetAttribute(reinterpret_cast<const void*>(&gemm8<0>),
                        hipFuncAttributeMaxDynamicSharedMemorySize, 131072);
    hipFuncSetAttribute(reinterpret_cast<const void*>(&gemm8<1>),
                        hipFuncAttributeMaxDynamicSharedMemorySize, 131072);

    prep<<<3348, 256, 0, stream>>>(query, Xb, Wq, Wk, Wv, Wu, Wo, Wcat,
                                   bq, bk, bv, bu, bo, bcat);
    gemm8<0><<<2048, 512, 131072, stream>>>(Xb, Wcat, bcat, qb, ktb, vtb, ub, nullptr);
    kv_partial<<<dim3(8, 64), 256, 0, stream>>>(ktb, vtb, kvp);
    kv_reduce<<<512, 256, 0, stream>>>(kvp, kvt);
    qkv_ln<<<512, 256, 0, stream>>>(qb, kvt, ub, lnw, lnb, yb);
    gemm8<1><<<512, 512, 131072, stream>>>(yb, Wcat + (size_t)4096 * 1024, bcat + 4096,
                                           nullptr, nullptr, nullptr, nullptr, out);
}